// Round 3
// baseline (467.945 us; speedup 1.0000x reference)
//
#include <hip/hip_runtime.h>
#include <hip/hip_cooperative_groups.h>

namespace cg = cooperative_groups;

// CenterLoss: loss = (1/B) * sum_i ||f_i - c_{l_i}||^2 / (counts_{l_i} * D)
// B=65536, D=512, C=1000, fp32 in / fp32 scalar out.
// Memory-bound: 128 MiB feature read -> ~21 us floor at 6.3 TB/s.
//
// Single cooperative kernel: zero counts -> sync -> histogram -> sync ->
// per-sample scaled distance (one wave per sample row, float4 loads) ->
// block reduce -> one atomicAdd per block -> sync -> write scalar.
// One dispatch total: removes memset + 2 kernel dispatch boundaries.

#define WAVE 64
constexpr int THREADS = 256;
constexpr int BLOCKS  = 1024;   // 4 waves/block -> 16 waves/CU worst case; co-resident

__global__ __launch_bounds__(THREADS) void centerloss_fused(
    const float* __restrict__ features,   // [batch, feat]
    const float* __restrict__ centers,    // [nclass, feat]
    const int*   __restrict__ labels,     // [batch]
    int*   __restrict__ counts,           // [nclass] (ws)
    float* __restrict__ accum,            // [1] (ws)
    float* __restrict__ out,              // [1]
    int batch, int feat, int nclass)
{
    cg::grid_group grid = cg::this_grid();
    const int tid      = blockIdx.x * blockDim.x + threadIdx.x;
    const int nthreads = gridDim.x * blockDim.x;

    // ---- Phase 0: zero the ws accumulators (ws is poisoned to 0xAA) ----
    for (int j = tid; j < nclass; j += nthreads) counts[j] = 0;
    if (tid == 0) *accum = 0.0f;
    grid.sync();

    // ---- Phase 1: label histogram ----
    for (int i = tid; i < batch; i += nthreads)
        atomicAdd(&counts[labels[i]], 1);
    grid.sync();

    // ---- Phase 2: per-sample squared distance, scaled by 1/count ----
    const int wave_id = tid >> 6;
    const int lane    = tid & 63;
    const int nwaves  = nthreads >> 6;        // 4096
    const int n4      = feat >> 2;            // 128 float4 per row

    float local = 0.0f;
    for (int sample = wave_id; sample < batch; sample += nwaves) {
        const int label = labels[sample];
        const float4* __restrict__ f4 =
            (const float4*)(features + (size_t)sample * feat);
        const float4* __restrict__ c4 =
            (const float4*)(centers + (size_t)label * feat);

        float acc = 0.0f;
#pragma unroll 2
        for (int idx = lane; idx < n4; idx += WAVE) {
            float4 fv = f4[idx];
            float4 cv = c4[idx];
            float dx = fv.x - cv.x;
            float dy = fv.y - cv.y;
            float dz = fv.z - cv.z;
            float dw = fv.w - cv.w;
            acc += dx * dx + dy * dy + dz * dz + dw * dw;
        }
        // counts[label] >= 1 whenever label appears in batch
        local += acc / (float)counts[label];
    }
    local *= 1.0f / (float)feat;

    // wave-64 butterfly reduce
#pragma unroll
    for (int off = 32; off > 0; off >>= 1)
        local += __shfl_down(local, off, WAVE);

    __shared__ float wpart[THREADS / WAVE];
    const int wib = threadIdx.x >> 6;
    if (lane == 0) wpart[wib] = local;
    __syncthreads();
    if (threadIdx.x == 0) {
        float b = 0.0f;
#pragma unroll
        for (int w = 0; w < THREADS / WAVE; ++w) b += wpart[w];
        atomicAdd(accum, b);               // 1024 adds to one line
    }
    grid.sync();

    // ---- Phase 3: final scalar ----
    if (tid == 0) out[0] = *accum / (float)batch;
}

extern "C" void kernel_launch(void* const* d_in, const int* in_sizes, int n_in,
                              void* d_out, int out_size, void* d_ws, size_t ws_size,
                              hipStream_t stream) {
    const float* features = (const float*)d_in[0];
    const float* centers  = (const float*)d_in[1];
    const int*   labels   = (const int*)d_in[2];
    float*       out      = (float*)d_out;

    int batch  = in_sizes[2];                 // 65536
    int feat   = in_sizes[0] / batch;         // 512
    int nclass = in_sizes[1] / feat;          // 1000

    int*   counts = (int*)d_ws;
    float* accum  = (float*)((char*)d_ws + ((nclass * sizeof(int) + 255) & ~255));

    void* args[] = {
        (void*)&features, (void*)&centers, (void*)&labels,
        (void*)&counts, (void*)&accum, (void*)&out,
        (void*)&batch, (void*)&feat, (void*)&nclass
    };

    hipLaunchCooperativeKernel((const void*)centerloss_fused,
                               dim3(BLOCKS), dim3(THREADS),
                               args, 0, stream);
}